// Round 3
// baseline (175.217 us; speedup 1.0000x reference)
//
#include <hip/hip_runtime.h>
#include <math.h>

// ---- compile-time physical constants (mirror the Python reference) ----
namespace k {
constexpr double dA     = 0.129907 + 0.095724;       // L_X + L_Y
constexpr double dR     = 4.0 * 0.0254;              // wheel radius
constexpr double dI     = 6.0;                       // inertia (== mass)
constexpr double dMOI   = 6.0 * (12.0 * 0.0254) * (12.0 * 0.0254) / 6.0;
constexpr float T_STALL   = (float)(5.4 / 100.0);
constexpr float INV_WFREE = (float)(1.0 / (1620.0 / 60.0 * 2.0 * 3.14159265358979323846));
constexpr float A         = (float)dA;
constexpr float INV_R     = (float)(1.0 / dR);
constexpr float INV_RI    = (float)(1.0 / (dR * dI));    // WT2LA rows 0,1 scale
constexpr float A_RMOI    = (float)(dA / (dR * dMOI));   // WT2LA row 2 scale
}

__device__ __forceinline__ float wheel_torque(float w, float m) {
    float p = m * w;
    // jnp.sign semantics: sign(0)=0 -> is_same_direction = 0.5
    float sgn = (float)(p > 0.0f) - (float)(p < 0.0f);
    float isd = 0.5f * (sgn + 1.0f);
    return k::T_STALL * (1.0f - fabsf(w) * isd * k::INV_WFREE) * m;
}

// One batch element: st[0..5] = state row, m0..m3 = motor duty, o[0..5] = out row
__device__ __forceinline__ void mecanum_elem(const float st[6],
                                             float m0, float m1, float m2, float m3,
                                             float o[6]) {
    float theta = st[2];
    float s, c;
    sincosf(theta, &s, &c);

    float v0 = st[3], v1 = st[4], v2 = st[5];

    // a2l = rot(cos(-t), sin(-t)) -> [[c, s, 0], [-s, c, 0], [0,0,1]]
    float lv0 = c * v0 + s * v1;
    float lv1 = c * v1 - s * v0;

    // wheel_vel = LV2WV @ local_vel; rows [1,-1,-A],[1,1,A],[1,1,-A],[1,-1,A], /R
    float al2 = k::A * v2;
    float w0 = (lv0 - lv1 - al2) * k::INV_R;
    float w1 = (lv0 + lv1 + al2) * k::INV_R;
    float w2 = (lv0 + lv1 - al2) * k::INV_R;
    float w3 = (lv0 - lv1 + al2) * k::INV_R;

    float t0 = wheel_torque(w0, m0);
    float t1 = wheel_torque(w1, m1);
    float t2 = wheel_torque(w2, m2);
    float t3 = wheel_torque(w3, m3);

    // local_accel = WT2LA @ torque
    float la0 = (t0 + t1 + t2 + t3) * k::INV_RI;
    float la1 = (-t0 + t1 + t2 - t3) * k::INV_RI;
    float la2 = (-t0 + t1 - t2 + t3) * k::A_RMOI;

    // l2a = rot(cos(t), sin(t)) -> [[c,-s,0],[s,c,0],[0,0,1]]
    float aa0 = c * la0 - s * la1;
    float aa1 = s * la0 + c * la1;

    o[0] = v0; o[1] = v1; o[2] = v2;
    o[3] = aa0; o[4] = aa1; o[5] = la2;
}

// Barrier-free per-wave LDS staging:
//   - each wave owns a private 192-float4 tile (its 64 pairs = 128 elements)
//   - DS ops from one wave execute in order, so global->LDS->compute->LDS->
//     global needs NO __syncthreads (all exchange is intra-wave)
//   - single buffer reused for input and output (in-order DS makes WAR safe)
//   - 12 KB LDS/block -> LDS no longer caps occupancy (8 blocks/CU possible)
#define BLOCK            256
#define WAVES_PER_BLOCK  4
#define PAIRS_PER_WAVE   64
#define F4_PER_WAVE      192   // 64 pairs * 3 float4

__global__ __launch_bounds__(256) void mecanum_wave_kernel(
    const float4* __restrict__ state4,
    const float* __restrict__ cd,
    float4* __restrict__ out4,
    int n_pairs) {
    __shared__ float4 sbuf[WAVES_PER_BLOCK * F4_PER_WAVE];   // 12 KB

    const int tid  = threadIdx.x;
    const int wid  = tid >> 6;
    const int lane = tid & 63;
    float4* ws = sbuf + wid * F4_PER_WAVE;

    const int pair0  = blockIdx.x * BLOCK + wid * PAIRS_PER_WAVE;
    const int f4base = pair0 * 3;
    const int total4 = n_pairs * 3;

    // batch-uniform motor duty: CD2MD @ control_duty (wave-uniform loads)
    float u0 = cd[0], u1 = cd[1], u2 = cd[2];
    float m0 = u0 - u1 - u2;
    float m1 = u0 + u1 + u2;
    float m2 = u0 + u1 - u2;
    float m3 = u0 - u1 + u2;

    // ---- stage 1: coalesced global -> LDS (lane-contiguous float4) ----
#pragma unroll
    for (int j = 0; j < 3; ++j) {
        int g = f4base + j * 64 + lane;
        if (g < total4) ws[j * 64 + lane] = state4[g];
    }

    // ---- stage 2: compute this lane's pair from LDS, write results back ----
    if (pair0 + lane < n_pairs) {
        float4 a  = ws[3 * lane + 0];
        float4 b  = ws[3 * lane + 1];
        float4 gg = ws[3 * lane + 2];

        float stA[6] = { a.x, a.y, a.z, a.w, b.x, b.y };
        float stB[6] = { b.z, b.w, gg.x, gg.y, gg.z, gg.w };
        float oA[6], oB[6];
        mecanum_elem(stA, m0, m1, m2, m3, oA);
        mecanum_elem(stB, m0, m1, m2, m3, oB);

        ws[3 * lane + 0] = make_float4(oA[0], oA[1], oA[2], oA[3]);
        ws[3 * lane + 1] = make_float4(oA[4], oA[5], oB[0], oB[1]);
        ws[3 * lane + 2] = make_float4(oB[2], oB[3], oB[4], oB[5]);
    }

    // ---- stage 3: coalesced LDS -> global ----
#pragma unroll
    for (int j = 0; j < 3; ++j) {
        int g = f4base + j * 64 + lane;
        if (g < total4) out4[g] = ws[j * 64 + lane];
    }
}

// Scalar tail for odd batch sizes (defensive; BATCH=4M is even).
__global__ void mecanum_tail_kernel(const float* __restrict__ state,
                                    const float* __restrict__ cd,
                                    float* __restrict__ out,
                                    int start, int n) {
    int i = start + blockIdx.x * blockDim.x + threadIdx.x;
    if (i >= n) return;
    float u0 = cd[0], u1 = cd[1], u2 = cd[2];
    float m0 = u0 - u1 - u2;
    float m1 = u0 + u1 + u2;
    float m2 = u0 + u1 - u2;
    float m3 = u0 - u1 + u2;
    float st[6], o[6];
#pragma unroll
    for (int j = 0; j < 6; ++j) st[j] = state[6 * i + j];
    mecanum_elem(st, m0, m1, m2, m3, o);
#pragma unroll
    for (int j = 0; j < 6; ++j) out[6 * i + j] = o[j];
}

extern "C" void kernel_launch(void* const* d_in, const int* in_sizes, int n_in,
                              void* d_out, int out_size, void* d_ws, size_t ws_size,
                              hipStream_t stream) {
    // inputs: d_in[0] = t (1, unused), d_in[1] = state (BATCH*6), d_in[2] = control_duty (3)
    const float* state = (const float*)d_in[1];
    const float* cd    = (const float*)d_in[2];
    float* out         = (float*)d_out;

    int n = in_sizes[1] / 6;        // batch size
    int n_pairs = n / 2;

    if (n_pairs > 0) {
        int grid = (n_pairs + BLOCK - 1) / BLOCK;
        mecanum_wave_kernel<<<grid, BLOCK, 0, stream>>>(
            (const float4*)state, cd, (float4*)out, n_pairs);
    }
    if (n & 1) {
        mecanum_tail_kernel<<<1, 64, 0, stream>>>(state, cd, out, 2 * n_pairs, n);
    }
}